// Round 8
// baseline (267.900 us; speedup 1.0000x reference)
//
#include <hip/hip_runtime.h>

#define MAX_TRUE 128

// anchors per (scale, anchor): ANCHOR_MASK = [[6,7,8],[3,4,5],[0,1,2]]
__device__ const float d_anch[3][3][2] = {
    {{116.f, 90.f}, {156.f, 198.f}, {373.f, 326.f}},
    {{30.f, 61.f}, {62.f, 45.f}, {59.f, 119.f}},
    {{10.f, 13.f}, {16.f, 30.f}, {33.f, 23.f}},
};

__device__ __forceinline__ float softplusf_(float x) {
    return fmaxf(x, 0.0f) + log1pf(expf(-fabsf(x)));
}
__device__ __forceinline__ float bcef_(float l, float t) {
    return softplusf_(l) - l * t;
}
__device__ __forceinline__ float sigmoidf_(float x) {
    return 1.0f / (1.0f + expf(-x));
}

// ---------------------------------------------------------------------------
// K1: candidate discovery + obj-cell losses, fused. One thread per cell.
// grid: 1440 blocks of 256 = (16 b x 5 chunks)s0 + (16 x 17)s1 + (16 x 68)s2.
// Writes: objmask byte per cell; per-chunk candidate area + count (write-only,
// no zeroing needed); per-block 4-component loss partial (always written).
// ---------------------------------------------------------------------------
__global__ void cand_obj_kernel(const float* __restrict__ yt0, const float* __restrict__ yt1,
                                const float* __restrict__ yt2,
                                const float* __restrict__ fm0, const float* __restrict__ fm1,
                                const float* __restrict__ fm2,
                                unsigned char* __restrict__ objmask,
                                float* __restrict__ chunkdata, int* __restrict__ chunkcnt,
                                float* __restrict__ objpart) {
    __shared__ int wcnt[4];
    __shared__ float wred[4][4];
    int bid = blockIdx.x, tid = threadIdx.x;
    int wid = tid >> 6, lane = tid & 63;
    int s, b, chunk, Sdim, objofs;
    const float *yt, *fm;
    if (bid < 80)       { s = 0; b = bid / 5;  chunk = bid - b * 5;  Sdim = 19; objofs = 0;     yt = yt0; fm = fm0; }
    else if (bid < 352) { s = 1; int l = bid - 80;  b = l / 17; chunk = l - b * 17; Sdim = 38; objofs = 17328; yt = yt1; fm = fm1; }
    else                { s = 2; int l = bid - 352; b = l / 68; chunk = l - b * 68; Sdim = 76; objofs = 86640; yt = yt2; fm = fm2; }
    int HW = Sdim * Sdim, spb = HW * 3;
    int cell = chunk * 256 + tid;
    bool valid = cell < spb;
    const float* src = yt + ((size_t)b * spb + cell) * 85;
    float obj = valid ? src[4] : 0.f;
    bool isobj = obj > 0.5f;
    if (valid) objmask[objofs + b * spb + cell] = isobj ? 1 : 0;
    unsigned long long m = __ballot(isobj);
    int wofs = __popcll(m & ((1ull << lane) - 1ull));
    if (lane == 0) wcnt[wid] = __popcll(m);
    __syncthreads();
    int base = 0;
    #pragma unroll
    for (int i = 0; i < 4; ++i) if (i < wid) base += wcnt[i];
    int total = wcnt[0] + wcnt[1] + wcnt[2] + wcnt[3];
    float axy = 0.f, awh = 0.f, aconf = 0.f, acls = 0.f;
    if (isobj) {
        float x = src[0], y = src[1], w = src[2], h = src[3];
        int pos = base + wofs;
        float* d = chunkdata + ((size_t)bid * 256 + pos) * 5;
        d[0] = x; d[1] = y; d[2] = w; d[3] = h;
        ((int*)d)[4] = cell;
        // obj-cell losses, computed in-place
        int hw = cell / 3, a = cell - hw * 3;
        int hh = hw / Sdim, ww = hw - hh * Sdim;
        const float* f = fm + ((size_t)(b * 255 + a * 85)) * HW + hw;
        float l0 = f[0], l1 = f[(size_t)HW], l2 = f[2 * (size_t)HW],
              l3 = f[3 * (size_t)HW], l4 = f[4 * (size_t)HW];
        float bscale = 2.f - w * h;
        axy = bscale * (bcef_(l0, x * (float)Sdim - (float)ww) +
                        bcef_(l1, y * (float)Sdim - (float)hh));
        float tw = logf(w / d_anch[s][a][0] * 608.f);
        float th = logf(h / d_anch[s][a][1] * 608.f);
        float dw = l2 - tw, dh = l3 - th;
        awh = bscale * (dw * dw + dh * dh);
        aconf = bcef_(l4, 1.0f);
        float c = 0.f;
        for (int k = 0; k < 80; ++k)
            c += bcef_(f[(size_t)(5 + k) * HW], src[5 + k]);
        acls = c;
    }
    if (tid == 0) chunkcnt[bid] = total;
    // block-reduce the 4 loss components -> objpart[bid]
    #pragma unroll
    for (int o = 32; o > 0; o >>= 1) {
        axy += __shfl_down(axy, o);
        awh += __shfl_down(awh, o);
        aconf += __shfl_down(aconf, o);
        acls += __shfl_down(acls, o);
    }
    if (lane == 0) {
        wred[wid][0] = axy; wred[wid][1] = awh;
        wred[wid][2] = aconf; wred[wid][3] = acls;
    }
    __syncthreads();
    if (tid == 0) {
        float* op = objpart + (size_t)bid * 4;
        op[0] = wred[0][0] + wred[1][0] + wred[2][0] + wred[3][0];
        op[1] = wred[0][1] + wred[1][1] + wred[2][1] + wred[3][1];
        op[2] = wred[0][2] + wred[1][2] + wred[2][2] + wred[3][2];
        op[3] = wred[0][3] + wred[1][3] + wred[2][3] + wred[3][3];
    }
}

// ---------------------------------------------------------------------------
// K2: per-slot box table from chunk areas. Chunks are scanned in ascending
// cell order and entries within a chunk are cell-ordered, so the first 128
// globally == reference's stable argsort take (no sort needed, ever).
// Pads to exactly 128 with zero boxes (IoU-neutral). Zeroes `done`.
// ---------------------------------------------------------------------------
__global__ void select_boxes(const float* __restrict__ chunkdata, const int* __restrict__ chunkcnt,
                             float4* __restrict__ boxesA, float* __restrict__ boxesT,
                             int* __restrict__ counts, int* __restrict__ done) {
    __shared__ int pre[69];
    int slot = blockIdx.x;  // 48
    int t = threadIdx.x;    // 256
    int s = slot >> 4, b = slot & 15;
    int base, nch;
    if (s == 0)      { base = b * 5;        nch = 5;  }
    else if (s == 1) { base = 80 + b * 17;  nch = 17; }
    else             { base = 352 + b * 68; nch = 68; }
    if (t == 0) {
        int acc = 0;
        for (int c = 0; c < nch; ++c) { pre[c] = acc; acc += chunkcnt[base + c]; }
        pre[nch] = acc;
        counts[slot] = min(acc, MAX_TRUE);
        if (slot == 0) *done = 0;
    }
    __syncthreads();
    int total = pre[nch];
    for (int c = 0; c < nch; ++c) {
        int p0 = pre[c];
        if (p0 >= MAX_TRUE) break;
        int n = pre[c + 1] - p0;
        if (t < n) {
            int p = p0 + t;
            if (p < MAX_TRUE) {
                const float* e = chunkdata + ((size_t)(base + c) * 256 + t) * 5;
                float x = e[0], y = e[1], w = e[2], h = e[3];
                float4 r;
                r.x = x - 0.5f * w; r.y = y - 0.5f * h;
                r.z = x + 0.5f * w; r.w = y + 0.5f * h;
                boxesA[slot * MAX_TRUE + p] = r;
                boxesT[slot * MAX_TRUE + p] = w * h;
            }
        }
    }
    int t128 = min(total, MAX_TRUE);
    for (int p = t128 + t; p < MAX_TRUE; p += 256) {
        boxesA[slot * MAX_TRUE + p] = make_float4(0.f, 0.f, 0.f, 0.f);
        boxesT[slot * MAX_TRUE + p] = 0.f;
    }
}

// ---------------------------------------------------------------------------
// K3: dense non-obj conf loss + fused final reduction (last-block-done).
// 2928 blocks x 128 threads.
// ---------------------------------------------------------------------------
__global__ void conf_kernel(const float* __restrict__ fm0, const float* __restrict__ fm1,
                            const float* __restrict__ fm2,
                            const unsigned char* __restrict__ objmask,
                            const float4* __restrict__ boxesA, const float* __restrict__ boxesT,
                            const int* __restrict__ counts,
                            float* __restrict__ partials, const float* __restrict__ objpart,
                            int* __restrict__ done, float* __restrict__ out) {
    __shared__ float4 sA[MAX_TRUE];
    __shared__ float sT[MAX_TRUE];
    __shared__ int isLast;
    __shared__ float red[2][5];
    int bid = blockIdx.x;
    int s, local, lnb, Sdim, objofs, spb;
    const float* fm;
    if (bid < 144)      { s = 0; local = bid;       lnb = 3;  Sdim = 19; objofs = 0;     spb = 1083;  fm = fm0; }
    else if (bid < 720) { s = 1; local = bid - 144; lnb = 12; Sdim = 38; objofs = 17328; spb = 4332;  fm = fm1; }
    else                { s = 2; local = bid - 720; lnb = 46; Sdim = 76; objofs = 86640; spb = 17328; fm = fm2; }
    int ba = local / lnb;
    int chunk = local - ba * lnb;
    int a = ba % 3, b = ba / 3;
    int slot = s * 16 + b;
    int tid = threadIdx.x;  // 128
    sA[tid] = boxesA[slot * MAX_TRUE + tid];
    sT[tid] = boxesT[slot * MAX_TRUE + tid];
    __syncthreads();
    int kr = (counts[slot] + 3) & ~3;
    int HW = Sdim * Sdim;
    int hw = chunk * 128 + tid;
    float lconf = 0.f;
    if (hw < HW) {
        int ob = objmask[objofs + b * spb + hw * 3 + a];
        const float* f = fm + ((size_t)(b * 255 + a * 85)) * HW + hw;
        float l0 = f[0], l1 = f[(size_t)HW], l2 = f[2 * (size_t)HW],
              l3 = f[3 * (size_t)HW], l4 = f[4 * (size_t)HW];
        if (!ob) {
            int h = hw / Sdim, w = hw - h * Sdim;
            float aw = d_anch[s][a][0], ah = d_anch[s][a][1];
            const float inv_in = 1.0f / 608.0f;
            float px = (sigmoidf_(l0) + (float)w) / (float)Sdim;
            float py = (sigmoidf_(l1) + (float)h) / (float)Sdim;
            float pw = aw * expf(l2) * inv_in;
            float ph = ah * expf(l3) * inv_in;
            float pminx = px - 0.5f * pw, pmaxx = px + 0.5f * pw;
            float pminy = py - 0.5f * ph, pmaxy = py + 0.5f * ph;
            float pa = pw * ph;
            // best_iou < 0.5  <=>  max_i(3*inter_i - ta_i) < pa
            float m0 = 0.f, m1 = 0.f, m2 = 0.f, m3 = 0.f;
            for (int i = 0; i < kr; i += 4) {
                float4 b0 = sA[i], b1 = sA[i + 1], b2 = sA[i + 2], b3 = sA[i + 3];
                float t0 = sT[i], t1 = sT[i + 1], t2 = sT[i + 2], t3 = sT[i + 3];
                float ix, iy;
                ix = fmaxf(fminf(pmaxx, b0.z) - fmaxf(pminx, b0.x), 0.f);
                iy = fmaxf(fminf(pmaxy, b0.w) - fmaxf(pminy, b0.y), 0.f);
                m0 = fmaxf(m0, fmaf(3.0f, ix * iy, -t0));
                ix = fmaxf(fminf(pmaxx, b1.z) - fmaxf(pminx, b1.x), 0.f);
                iy = fmaxf(fminf(pmaxy, b1.w) - fmaxf(pminy, b1.y), 0.f);
                m1 = fmaxf(m1, fmaf(3.0f, ix * iy, -t1));
                ix = fmaxf(fminf(pmaxx, b2.z) - fmaxf(pminx, b2.x), 0.f);
                iy = fmaxf(fminf(pmaxy, b2.w) - fmaxf(pminy, b2.y), 0.f);
                m2 = fmaxf(m2, fmaf(3.0f, ix * iy, -t2));
                ix = fmaxf(fminf(pmaxx, b3.z) - fmaxf(pminx, b3.x), 0.f);
                iy = fmaxf(fminf(pmaxy, b3.w) - fmaxf(pminy, b3.y), 0.f);
                m3 = fmaxf(m3, fmaf(3.0f, ix * iy, -t3));
            }
            float m = fmaxf(fmaxf(m0, m1), fmaxf(m2, m3));
            lconf = (m < pa) ? softplusf_(l4) : 0.f;
        }
    }
    int wid = tid >> 6;
    #pragma unroll
    for (int o = 32; o > 0; o >>= 1)
        lconf += __shfl_down(lconf, o);
    if ((tid & 63) == 0)
        partials[bid * 2 + wid] = lconf;
    // last-block finalize
    __threadfence();
    if (tid == 0) {
        int old = atomicAdd(done, 1);
        isLast = (old == (int)gridDim.x - 1) ? 1 : 0;
    }
    __syncthreads();
    if (isLast) {
        float cno = 0.f;
        for (int i = tid; i < 5856; i += 128)
            cno += __hip_atomic_load(&partials[i], __ATOMIC_RELAXED, __HIP_MEMORY_SCOPE_AGENT);
        float xy = 0.f, wh = 0.f, co = 0.f, cl = 0.f;
        for (int i = tid; i < 1440; i += 128) {
            const float* op = objpart + (size_t)i * 4;
            xy += op[0]; wh += op[1]; co += op[2]; cl += op[3];
        }
        int lane = tid & 63;
        #pragma unroll
        for (int o = 32; o > 0; o >>= 1) {
            cno += __shfl_down(cno, o);
            xy += __shfl_down(xy, o);
            wh += __shfl_down(wh, o);
            co += __shfl_down(co, o);
            cl += __shfl_down(cl, o);
        }
        if (lane == 0) {
            red[wid][0] = cno; red[wid][1] = xy; red[wid][2] = wh;
            red[wid][3] = co;  red[wid][4] = cl;
        }
        __syncthreads();
        if (tid == 0) {
            float conf = red[0][0] + red[1][0] + red[0][3] + red[1][3];
            float txy = red[0][1] + red[1][1];
            float twh = red[0][2] + red[1][2];
            float tcl = red[0][4] + red[1][4];
            const float invB = 1.0f / 16.0f;
            float a0 = txy * invB;
            float a1 = twh * invB;
            float a2 = conf * invB;
            float a3 = tcl * invB;
            out[1] = a0; out[2] = a1; out[3] = a2; out[4] = a3;
            out[0] = a0 + a1 + a2 + a3;
        }
    }
}

extern "C" void kernel_launch(void* const* d_in, const int* in_sizes, int n_in,
                              void* d_out, int out_size, void* d_ws, size_t ws_size,
                              hipStream_t stream) {
    const float* fm0 = (const float*)d_in[0];
    const float* fm1 = (const float*)d_in[1];
    const float* fm2 = (const float*)d_in[2];
    const float* yt0 = (const float*)d_in[3];
    const float* yt1 = (const float*)d_in[4];
    const float* yt2 = (const float*)d_in[5];
    float* out = (float*)d_out;

    // workspace layout (bytes); nothing needs pre-zeroing.
    char* ws = (char*)d_ws;
    int* chunkcnt = (int*)ws;                              // 1440*4   = 5760
    int* counts = (int*)(ws + 5760);                       // 48*4     = 192
    int* done = (int*)(ws + 5952);                         // 4 (pad to 6016)
    float* objpart = (float*)(ws + 6016);                  // 1440*4*4 = 23040
    float* partials = (float*)(ws + 29056);                // 5856*4   = 23424
    float4* boxesA = (float4*)(ws + 52480);                // 48*128*16= 98304
    float* boxesT = (float*)(ws + 150784);                 // 48*128*4 = 24576
    unsigned char* objmask = (unsigned char*)(ws + 175360);// 363888
    float* chunkdata = (float*)(ws + 539264);              // 1440*256*5*4 = 7372800

    cand_obj_kernel<<<1440, 256, 0, stream>>>(yt0, yt1, yt2, fm0, fm1, fm2,
                                              objmask, chunkdata, chunkcnt, objpart);
    select_boxes<<<48, 256, 0, stream>>>(chunkdata, chunkcnt, boxesA, boxesT, counts, done);
    conf_kernel<<<2928, 128, 0, stream>>>(fm0, fm1, fm2, objmask, boxesA, boxesT, counts,
                                          partials, objpart, done, out);
}

// Round 9
// 44.961 us; speedup vs baseline: 5.9585x; 5.9585x over previous
//
#include <hip/hip_runtime.h>

#define MAX_TRUE 128

// anchors per (scale, anchor): ANCHOR_MASK = [[6,7,8],[3,4,5],[0,1,2]]
__device__ const float d_anch[3][3][2] = {
    {{116.f, 90.f}, {156.f, 198.f}, {373.f, 326.f}},
    {{30.f, 61.f}, {62.f, 45.f}, {59.f, 119.f}},
    {{10.f, 13.f}, {16.f, 30.f}, {33.f, 23.f}},
};

__device__ __forceinline__ float softplusf_(float x) {
    return fmaxf(x, 0.0f) + log1pf(expf(-fabsf(x)));
}
__device__ __forceinline__ float bcef_(float l, float t) {
    return softplusf_(l) - l * t;
}
__device__ __forceinline__ float sigmoidf_(float x) {
    return 1.0f / (1.0f + expf(-x));
}

// ---------------------------------------------------------------------------
// K1: candidate discovery only. One thread per cell, 1440 blocks of 256.
// Chunk-local ballot compaction: no atomics, no pre-zeroing. Writes objmask,
// chunkdata[bid][*][5], chunkcnt[bid] (always).
// ---------------------------------------------------------------------------
__global__ void cand_kernel(const float* __restrict__ yt0, const float* __restrict__ yt1,
                            const float* __restrict__ yt2,
                            unsigned char* __restrict__ objmask,
                            float* __restrict__ chunkdata, int* __restrict__ chunkcnt) {
    __shared__ int wcnt[4];
    int bid = blockIdx.x, tid = threadIdx.x;
    int wid = tid >> 6, lane = tid & 63;
    int s, b, chunk, spb, objofs;
    const float* yt;
    if (bid < 80)       { s = 0; b = bid / 5;  chunk = bid - b * 5;  spb = 1083;  objofs = 0;     yt = yt0; }
    else if (bid < 352) { int l = bid - 80;  s = 1; b = l / 17; chunk = l - b * 17; spb = 4332;  objofs = 17328; yt = yt1; }
    else                { int l = bid - 352; s = 2; b = l / 68; chunk = l - b * 68; spb = 17328; objofs = 86640; yt = yt2; }
    int cell = chunk * 256 + tid;
    bool valid = cell < spb;
    const float* src = yt + ((size_t)b * spb + cell) * 85;
    float obj = valid ? src[4] : 0.f;
    bool isobj = obj > 0.5f;
    if (valid) objmask[objofs + b * spb + cell] = isobj ? 1 : 0;
    unsigned long long m = __ballot(isobj);
    int wofs = __popcll(m & ((1ull << lane) - 1ull));
    if (lane == 0) wcnt[wid] = __popcll(m);
    __syncthreads();
    int base = 0;
    #pragma unroll
    for (int i = 0; i < 4; ++i) if (i < wid) base += wcnt[i];
    if (isobj) {
        int pos = base + wofs;
        float* d = chunkdata + ((size_t)bid * 256 + pos) * 5;
        d[0] = src[0];
        d[1] = src[1];
        d[2] = src[2];
        d[3] = src[3];
        ((int*)d)[4] = cell;
    }
    if (tid == 0) chunkcnt[bid] = wcnt[0] + wcnt[1] + wcnt[2] + wcnt[3];
}

// ---------------------------------------------------------------------------
// K2: per-slot padded box table. Chunks scanned in ascending cell order ==
// reference's stable argsort order, so first 128 needs no sort. Thread t
// copies chunk t's few entries; pad to exactly 128 zero boxes.
// ---------------------------------------------------------------------------
__global__ void select_boxes(const float* __restrict__ chunkdata, const int* __restrict__ chunkcnt,
                             float4* __restrict__ boxesA, float* __restrict__ boxesT,
                             int* __restrict__ counts) {
    __shared__ int cnts[68];
    __shared__ int pre[69];
    int slot = blockIdx.x;  // 48
    int t = threadIdx.x;    // 256
    int s = slot >> 4, b = slot & 15;
    int base, nch;
    if (s == 0)      { base = b * 5;        nch = 5;  }
    else if (s == 1) { base = 80 + b * 17;  nch = 17; }
    else             { base = 352 + b * 68; nch = 68; }
    if (t < nch) cnts[t] = chunkcnt[base + t];
    __syncthreads();
    if (t == 0) {
        int acc = 0;
        for (int c = 0; c < nch; ++c) { pre[c] = acc; acc += cnts[c]; }
        pre[nch] = acc;
        counts[slot] = min(acc, MAX_TRUE);
    }
    __syncthreads();
    if (t < nch) {
        int n = cnts[t], p0 = pre[t];
        for (int j = 0; j < n; ++j) {
            int p = p0 + j;
            if (p >= MAX_TRUE) break;
            const float* e = chunkdata + ((size_t)(base + t) * 256 + j) * 5;
            float x = e[0], y = e[1], w = e[2], h = e[3];
            float4 r;
            r.x = x - 0.5f * w; r.y = y - 0.5f * h;
            r.z = x + 0.5f * w; r.w = y + 0.5f * h;
            boxesA[slot * MAX_TRUE + p] = r;
            boxesT[slot * MAX_TRUE + p] = w * h;
        }
    }
    __syncthreads();
    int t128 = min(pre[nch], MAX_TRUE);
    for (int p = t128 + t; p < MAX_TRUE; p += 256) {
        boxesA[slot * MAX_TRUE + p] = make_float4(0.f, 0.f, 0.f, 0.f);
        boxesT[slot * MAX_TRUE + p] = 0.f;
    }
}

// ---------------------------------------------------------------------------
// K3: fused grid, 2928 blocks x 256.
//   bid <  1488 : dense non-obj conf loss (256 cells/block) -> partials[bid]
//   bid >= 1488 : obj-cell losses, wave-per-candidate from chunkdata
//                 -> objpart[bid-1488][4] (always written)
// ---------------------------------------------------------------------------
__global__ void fused_kernel(const float* __restrict__ fm0, const float* __restrict__ fm1,
                             const float* __restrict__ fm2,
                             const float* __restrict__ yt0, const float* __restrict__ yt1,
                             const float* __restrict__ yt2,
                             const unsigned char* __restrict__ objmask,
                             const float4* __restrict__ boxesA, const float* __restrict__ boxesT,
                             const int* __restrict__ counts,
                             const float* __restrict__ chunkdata, const int* __restrict__ chunkcnt,
                             float* __restrict__ partials, float* __restrict__ objpart) {
    __shared__ float4 sA[MAX_TRUE];
    __shared__ float sT[MAX_TRUE];
    __shared__ float wred[4][4];
    int bid = blockIdx.x, tid = threadIdx.x;
    int wid = tid >> 6, lane = tid & 63;

    if (bid < 1488) {
        // ---- dense conf path ----
        int s, local, lnb, Sdim, objofs, spb;
        const float* fm;
        if (bid < 96)       { s = 0; local = bid;       lnb = 2;  Sdim = 19; objofs = 0;     spb = 1083;  fm = fm0; }
        else if (bid < 384) { s = 1; local = bid - 96;  lnb = 6;  Sdim = 38; objofs = 17328; spb = 4332;  fm = fm1; }
        else                { s = 2; local = bid - 384; lnb = 23; Sdim = 76; objofs = 86640; spb = 17328; fm = fm2; }
        int ba = local / lnb;
        int chunk = local - ba * lnb;
        int a = ba % 3, b = ba / 3;
        int slot = s * 16 + b;
        if (tid < MAX_TRUE) {
            sA[tid] = boxesA[slot * MAX_TRUE + tid];
            sT[tid] = boxesT[slot * MAX_TRUE + tid];
        }
        __syncthreads();
        int kr = (counts[slot] + 3) & ~3;
        int HW = Sdim * Sdim;
        int hw = chunk * 256 + tid;
        float lconf = 0.f;
        if (hw < HW) {
            int ob = objmask[objofs + b * spb + hw * 3 + a];
            const float* f = fm + ((size_t)(b * 255 + a * 85)) * HW + hw;
            float l0 = f[0], l1 = f[(size_t)HW], l2 = f[2 * (size_t)HW],
                  l3 = f[3 * (size_t)HW], l4 = f[4 * (size_t)HW];
            if (!ob) {
                int h = hw / Sdim, w = hw - h * Sdim;
                float aw = d_anch[s][a][0], ah = d_anch[s][a][1];
                const float inv_in = 1.0f / 608.0f;
                float px = (sigmoidf_(l0) + (float)w) / (float)Sdim;
                float py = (sigmoidf_(l1) + (float)h) / (float)Sdim;
                float pw = aw * expf(l2) * inv_in;
                float ph = ah * expf(l3) * inv_in;
                float pminx = px - 0.5f * pw, pmaxx = px + 0.5f * pw;
                float pminy = py - 0.5f * ph, pmaxy = py + 0.5f * ph;
                float pa = pw * ph;
                // best_iou < 0.5  <=>  max_i(3*inter_i - ta_i) < pa
                float m0 = 0.f, m1 = 0.f, m2 = 0.f, m3 = 0.f;
                for (int i = 0; i < kr; i += 4) {
                    float4 b0 = sA[i], b1 = sA[i + 1], b2 = sA[i + 2], b3 = sA[i + 3];
                    float t0 = sT[i], t1 = sT[i + 1], t2 = sT[i + 2], t3 = sT[i + 3];
                    float ix, iy;
                    ix = fmaxf(fminf(pmaxx, b0.z) - fmaxf(pminx, b0.x), 0.f);
                    iy = fmaxf(fminf(pmaxy, b0.w) - fmaxf(pminy, b0.y), 0.f);
                    m0 = fmaxf(m0, fmaf(3.0f, ix * iy, -t0));
                    ix = fmaxf(fminf(pmaxx, b1.z) - fmaxf(pminx, b1.x), 0.f);
                    iy = fmaxf(fminf(pmaxy, b1.w) - fmaxf(pminy, b1.y), 0.f);
                    m1 = fmaxf(m1, fmaf(3.0f, ix * iy, -t1));
                    ix = fmaxf(fminf(pmaxx, b2.z) - fmaxf(pminx, b2.x), 0.f);
                    iy = fmaxf(fminf(pmaxy, b2.w) - fmaxf(pminy, b2.y), 0.f);
                    m2 = fmaxf(m2, fmaf(3.0f, ix * iy, -t2));
                    ix = fmaxf(fminf(pmaxx, b3.z) - fmaxf(pminx, b3.x), 0.f);
                    iy = fmaxf(fminf(pmaxy, b3.w) - fmaxf(pminy, b3.y), 0.f);
                    m3 = fmaxf(m3, fmaf(3.0f, ix * iy, -t3));
                }
                float m = fmaxf(fmaxf(m0, m1), fmaxf(m2, m3));
                lconf = (m < pa) ? softplusf_(l4) : 0.f;
            }
        }
        #pragma unroll
        for (int o = 32; o > 0; o >>= 1)
            lconf += __shfl_down(lconf, o);
        if (lane == 0) wred[wid][0] = lconf;
        __syncthreads();
        if (tid == 0)
            partials[bid] = wred[0][0] + wred[1][0] + wred[2][0] + wred[3][0];
    } else {
        // ---- obj-loss path: one chunk per block, wave per candidate ----
        int cid = bid - 1488;  // 0..1439, same mapping as cand_kernel
        int n = chunkcnt[cid];
        float* op = objpart + (size_t)cid * 4;
        if (n == 0) {
            if (tid == 0) { op[0] = 0.f; op[1] = 0.f; op[2] = 0.f; op[3] = 0.f; }
            return;
        }
        int s, b, spb, Sdim;
        const float *fm, *yt;
        if (cid < 80)       { s = 0; b = cid / 5;  spb = 1083;  Sdim = 19; fm = fm0; yt = yt0; }
        else if (cid < 352) { int l = cid - 80;  s = 1; b = l / 17; spb = 4332;  Sdim = 38; fm = fm1; yt = yt1; }
        else                { int l = cid - 352; s = 2; b = l / 68; spb = 17328; Sdim = 76; fm = fm2; yt = yt2; }
        int HW = Sdim * Sdim;
        float axy = 0.f, awh = 0.f, aconf = 0.f, acls = 0.f;
        for (int ci = wid; ci < n; ci += 4) {
            const float* cd = chunkdata + ((size_t)cid * 256 + ci) * 5;
            float x = cd[0], y = cd[1], w = cd[2], h = cd[3];
            int cell = ((const int*)cd)[4];
            int hw = cell / 3, a = cell - hw * 3;
            int hh = hw / Sdim, ww = hw - hh * Sdim;
            const float* f = fm + ((size_t)(b * 255 + a * 85)) * HW + hw;
            const float* yrow = yt + ((size_t)b * spb + cell) * 85;
            float cl = bcef_(f[(size_t)(5 + lane) * HW], yrow[5 + lane]);
            if (lane < 16) {
                int k2 = 64 + lane;
                cl += bcef_(f[(size_t)(5 + k2) * HW], yrow[5 + k2]);
            }
            acls += cl;
            float bscale = 2.f - w * h;
            if (lane < 5) {
                float lv = f[(size_t)lane * HW];
                if (lane == 0) axy += bscale * bcef_(lv, x * (float)Sdim - (float)ww);
                else if (lane == 1) axy += bscale * bcef_(lv, y * (float)Sdim - (float)hh);
                else if (lane == 2) {
                    float tw = logf(w / d_anch[s][a][0] * 608.f);
                    float d = lv - tw;
                    awh += bscale * d * d;
                } else if (lane == 3) {
                    float th = logf(h / d_anch[s][a][1] * 608.f);
                    float d = lv - th;
                    awh += bscale * d * d;
                } else {
                    aconf += bcef_(lv, 1.0f);
                }
            }
        }
        #pragma unroll
        for (int o = 32; o > 0; o >>= 1) {
            axy += __shfl_down(axy, o);
            awh += __shfl_down(awh, o);
            aconf += __shfl_down(aconf, o);
            acls += __shfl_down(acls, o);
        }
        if (lane == 0) {
            wred[wid][0] = axy; wred[wid][1] = awh;
            wred[wid][2] = aconf; wred[wid][3] = acls;
        }
        __syncthreads();
        if (tid == 0) {
            op[0] = wred[0][0] + wred[1][0] + wred[2][0] + wred[3][0];
            op[1] = wred[0][1] + wred[1][1] + wred[2][1] + wred[3][1];
            op[2] = wred[0][2] + wred[1][2] + wred[2][2] + wred[3][2];
            op[3] = wred[0][3] + wred[1][3] + wred[2][3] + wred[3][3];
        }
    }
}

// ---------------------------------------------------------------------------
// K4: final reduction of 1488 conf partials + 1440x4 obj partials.
// ---------------------------------------------------------------------------
__global__ void finalize_kernel(const float* __restrict__ partials,
                                const float* __restrict__ objpart,
                                float* __restrict__ out) {
    __shared__ float red[4][5];
    int tid = threadIdx.x;  // 256
    int wid = tid >> 6, lane = tid & 63;
    float cno = 0.f;
    for (int i = tid; i < 1488; i += 256) cno += partials[i];
    float xy = 0.f, wh = 0.f, co = 0.f, cl = 0.f;
    for (int i = tid; i < 1440; i += 256) {
        const float* op = objpart + (size_t)i * 4;
        xy += op[0]; wh += op[1]; co += op[2]; cl += op[3];
    }
    #pragma unroll
    for (int o = 32; o > 0; o >>= 1) {
        cno += __shfl_down(cno, o);
        xy += __shfl_down(xy, o);
        wh += __shfl_down(wh, o);
        co += __shfl_down(co, o);
        cl += __shfl_down(cl, o);
    }
    if (lane == 0) {
        red[wid][0] = cno; red[wid][1] = xy; red[wid][2] = wh;
        red[wid][3] = co;  red[wid][4] = cl;
    }
    __syncthreads();
    if (tid == 0) {
        float conf = 0.f, txy = 0.f, twh = 0.f, tcl = 0.f;
        for (int i = 0; i < 4; ++i) {
            conf += red[i][0] + red[i][3];
            txy += red[i][1]; twh += red[i][2]; tcl += red[i][4];
        }
        const float invB = 1.0f / 16.0f;
        float a0 = txy * invB;
        float a1 = twh * invB;
        float a2 = conf * invB;
        float a3 = tcl * invB;
        out[1] = a0; out[2] = a1; out[3] = a2; out[4] = a3;
        out[0] = a0 + a1 + a2 + a3;
    }
}

extern "C" void kernel_launch(void* const* d_in, const int* in_sizes, int n_in,
                              void* d_out, int out_size, void* d_ws, size_t ws_size,
                              hipStream_t stream) {
    const float* fm0 = (const float*)d_in[0];
    const float* fm1 = (const float*)d_in[1];
    const float* fm2 = (const float*)d_in[2];
    const float* yt0 = (const float*)d_in[3];
    const float* yt1 = (const float*)d_in[4];
    const float* yt2 = (const float*)d_in[5];
    float* out = (float*)d_out;

    // workspace layout (bytes); nothing needs pre-zeroing, no atomics anywhere.
    char* ws = (char*)d_ws;
    int* chunkcnt = (int*)ws;                               // 1440*4 = 5760
    int* counts = (int*)(ws + 5760);                        // 48*4   = 192
    float* partials = (float*)(ws + 5952);                  // 1488*4 = 5952
    float* objpart = (float*)(ws + 11904);                  // 1440*16= 23040
    float4* boxesA = (float4*)(ws + 34944);                 // 48*128*16 = 98304
    float* boxesT = (float*)(ws + 133248);                  // 48*128*4  = 24576
    unsigned char* objmask = (unsigned char*)(ws + 157824); // 363888
    float* chunkdata = (float*)(ws + 521728);               // 1440*256*5*4 = 7372800

    cand_kernel<<<1440, 256, 0, stream>>>(yt0, yt1, yt2, objmask, chunkdata, chunkcnt);
    select_boxes<<<48, 256, 0, stream>>>(chunkdata, chunkcnt, boxesA, boxesT, counts);
    fused_kernel<<<2928, 256, 0, stream>>>(fm0, fm1, fm2, yt0, yt1, yt2,
                                           objmask, boxesA, boxesT, counts,
                                           chunkdata, chunkcnt, partials, objpart);
    finalize_kernel<<<1, 256, 0, stream>>>(partials, objpart, out);
}

// Round 10
// 41.268 us; speedup vs baseline: 6.4916x; 1.0895x over previous
//
#include <hip/hip_runtime.h>

#define MAX_TRUE 128

// anchors per (scale, anchor): ANCHOR_MASK = [[6,7,8],[3,4,5],[0,1,2]]
__device__ const float d_anch[3][3][2] = {
    {{116.f, 90.f}, {156.f, 198.f}, {373.f, 326.f}},
    {{30.f, 61.f}, {62.f, 45.f}, {59.f, 119.f}},
    {{10.f, 13.f}, {16.f, 30.f}, {33.f, 23.f}},
};

__device__ __forceinline__ float softplusf_(float x) {
    return fmaxf(x, 0.0f) + log1pf(expf(-fabsf(x)));
}
__device__ __forceinline__ float bcef_(float l, float t) {
    return softplusf_(l) - l * t;
}
__device__ __forceinline__ float sigmoidf_(float x) {
    return 1.0f / (1.0f + expf(-x));
}

// ---------------------------------------------------------------------------
// K1: candidate discovery. One thread per cell, 1440 blocks of 256.
// Chunk-local ballot compaction: no atomics, no pre-zeroing. Writes objmask,
// chunkdata[bid][*][5], chunkcnt[bid] (always written).
// ---------------------------------------------------------------------------
__global__ void cand_kernel(const float* __restrict__ yt0, const float* __restrict__ yt1,
                            const float* __restrict__ yt2,
                            unsigned char* __restrict__ objmask,
                            float* __restrict__ chunkdata, int* __restrict__ chunkcnt) {
    __shared__ int wcnt[4];
    int bid = blockIdx.x, tid = threadIdx.x;
    int wid = tid >> 6, lane = tid & 63;
    int b, chunk, spb, objofs;
    const float* yt;
    if (bid < 80)       { b = bid / 5;  chunk = bid - b * 5;  spb = 1083;  objofs = 0;     yt = yt0; }
    else if (bid < 352) { int l = bid - 80;  b = l / 17; chunk = l - b * 17; spb = 4332;  objofs = 17328; yt = yt1; }
    else                { int l = bid - 352; b = l / 68; chunk = l - b * 68; spb = 17328; objofs = 86640; yt = yt2; }
    int cell = chunk * 256 + tid;
    bool valid = cell < spb;
    const float* src = yt + ((size_t)b * spb + cell) * 85;
    float obj = valid ? src[4] : 0.f;
    bool isobj = obj > 0.5f;
    if (valid) objmask[objofs + b * spb + cell] = isobj ? 1 : 0;
    unsigned long long m = __ballot(isobj);
    int wofs = __popcll(m & ((1ull << lane) - 1ull));
    if (lane == 0) wcnt[wid] = __popcll(m);
    __syncthreads();
    int base = 0;
    #pragma unroll
    for (int i = 0; i < 4; ++i) if (i < wid) base += wcnt[i];
    if (isobj) {
        int pos = base + wofs;
        float* d = chunkdata + ((size_t)bid * 256 + pos) * 5;
        d[0] = src[0];
        d[1] = src[1];
        d[2] = src[2];
        d[3] = src[3];
        ((int*)d)[4] = cell;
    }
    if (tid == 0) chunkcnt[bid] = wcnt[0] + wcnt[1] + wcnt[2] + wcnt[3];
}

// ---------------------------------------------------------------------------
// K2: fused grid, 2928 blocks x 256.
//   bid <  1488 : dense non-obj conf loss. The block first builds its slot's
//                 padded 128-entry box table DIRECTLY IN LDS from chunkdata
//                 (chunk ascending order == reference's stable argsort order,
//                 so first-128 truncation is exact; no sort, no global boxes).
//   bid >= 1488 : obj-cell losses, wave-per-candidate from chunkdata
//                 -> objpart[bid-1488][4] (always written)
// ---------------------------------------------------------------------------
__global__ void fused_kernel(const float* __restrict__ fm0, const float* __restrict__ fm1,
                             const float* __restrict__ fm2,
                             const float* __restrict__ yt0, const float* __restrict__ yt1,
                             const float* __restrict__ yt2,
                             const unsigned char* __restrict__ objmask,
                             const float* __restrict__ chunkdata, const int* __restrict__ chunkcnt,
                             float* __restrict__ partials, float* __restrict__ objpart) {
    __shared__ float4 sA[MAX_TRUE];
    __shared__ float sT[MAX_TRUE];
    __shared__ float wred[4][4];
    __shared__ int cnts[68];
    __shared__ int pre[69];
    int bid = blockIdx.x, tid = threadIdx.x;
    int wid = tid >> 6, lane = tid & 63;

    if (bid < 1488) {
        // ---- dense conf path ----
        int s, local, lnb, Sdim, objofs, spb;
        const float* fm;
        if (bid < 96)       { s = 0; local = bid;       lnb = 2;  Sdim = 19; objofs = 0;     spb = 1083;  fm = fm0; }
        else if (bid < 384) { s = 1; local = bid - 96;  lnb = 6;  Sdim = 38; objofs = 17328; spb = 4332;  fm = fm1; }
        else                { s = 2; local = bid - 384; lnb = 23; Sdim = 76; objofs = 86640; spb = 17328; fm = fm2; }
        int ba = local / lnb;
        int chunk = local - ba * lnb;
        int a = ba % 3, b = ba / 3;
        // in-block select: build slot's box table in LDS
        int cbase, nch;
        if (s == 0)      { cbase = b * 5;        nch = 5;  }
        else if (s == 1) { cbase = 80 + b * 17;  nch = 17; }
        else             { cbase = 352 + b * 68; nch = 68; }
        if (tid < nch) cnts[tid] = chunkcnt[cbase + tid];
        __syncthreads();
        if (tid == 0) {
            int acc = 0;
            for (int c = 0; c < nch; ++c) { pre[c] = acc; acc += cnts[c]; }
            pre[nch] = acc;
        }
        __syncthreads();
        int total = pre[nch];
        int t128 = min(total, MAX_TRUE);
        if (tid < nch) {
            int n = cnts[tid], p0 = pre[tid];
            for (int j = 0; j < n; ++j) {
                int p = p0 + j;
                if (p >= MAX_TRUE) break;
                const float* e = chunkdata + ((size_t)(cbase + tid) * 256 + j) * 5;
                float x = e[0], y = e[1], w = e[2], h = e[3];
                float4 r;
                r.x = x - 0.5f * w; r.y = y - 0.5f * h;
                r.z = x + 0.5f * w; r.w = y + 0.5f * h;
                sA[p] = r;
                sT[p] = w * h;
            }
        }
        for (int p = t128 + tid; p < MAX_TRUE; p += 256) {
            sA[p] = make_float4(0.f, 0.f, 0.f, 0.f);
            sT[p] = 0.f;
        }
        __syncthreads();
        int kr = (t128 + 3) & ~3;
        int HW = Sdim * Sdim;
        int hw = chunk * 256 + tid;
        float lconf = 0.f;
        if (hw < HW) {
            int ob = objmask[objofs + b * spb + hw * 3 + a];
            const float* f = fm + ((size_t)(b * 255 + a * 85)) * HW + hw;
            float l0 = f[0], l1 = f[(size_t)HW], l2 = f[2 * (size_t)HW],
                  l3 = f[3 * (size_t)HW], l4 = f[4 * (size_t)HW];
            if (!ob) {
                int h = hw / Sdim, w = hw - h * Sdim;
                float aw = d_anch[s][a][0], ah = d_anch[s][a][1];
                const float inv_in = 1.0f / 608.0f;
                float px = (sigmoidf_(l0) + (float)w) / (float)Sdim;
                float py = (sigmoidf_(l1) + (float)h) / (float)Sdim;
                float pw = aw * expf(l2) * inv_in;
                float ph = ah * expf(l3) * inv_in;
                float pminx = px - 0.5f * pw, pmaxx = px + 0.5f * pw;
                float pminy = py - 0.5f * ph, pmaxy = py + 0.5f * ph;
                float pa = pw * ph;
                // best_iou < 0.5  <=>  max_i(3*inter_i - ta_i) < pa
                float m0 = 0.f, m1 = 0.f, m2 = 0.f, m3 = 0.f;
                for (int i = 0; i < kr; i += 4) {
                    float4 b0 = sA[i], b1 = sA[i + 1], b2 = sA[i + 2], b3 = sA[i + 3];
                    float t0 = sT[i], t1 = sT[i + 1], t2 = sT[i + 2], t3 = sT[i + 3];
                    float ix, iy;
                    ix = fmaxf(fminf(pmaxx, b0.z) - fmaxf(pminx, b0.x), 0.f);
                    iy = fmaxf(fminf(pmaxy, b0.w) - fmaxf(pminy, b0.y), 0.f);
                    m0 = fmaxf(m0, fmaf(3.0f, ix * iy, -t0));
                    ix = fmaxf(fminf(pmaxx, b1.z) - fmaxf(pminx, b1.x), 0.f);
                    iy = fmaxf(fminf(pmaxy, b1.w) - fmaxf(pminy, b1.y), 0.f);
                    m1 = fmaxf(m1, fmaf(3.0f, ix * iy, -t1));
                    ix = fmaxf(fminf(pmaxx, b2.z) - fmaxf(pminx, b2.x), 0.f);
                    iy = fmaxf(fminf(pmaxy, b2.w) - fmaxf(pminy, b2.y), 0.f);
                    m2 = fmaxf(m2, fmaf(3.0f, ix * iy, -t2));
                    ix = fmaxf(fminf(pmaxx, b3.z) - fmaxf(pminx, b3.x), 0.f);
                    iy = fmaxf(fminf(pmaxy, b3.w) - fmaxf(pminy, b3.y), 0.f);
                    m3 = fmaxf(m3, fmaf(3.0f, ix * iy, -t3));
                }
                float m = fmaxf(fmaxf(m0, m1), fmaxf(m2, m3));
                lconf = (m < pa) ? softplusf_(l4) : 0.f;
            }
        }
        #pragma unroll
        for (int o = 32; o > 0; o >>= 1)
            lconf += __shfl_down(lconf, o);
        if (lane == 0) wred[wid][0] = lconf;
        __syncthreads();
        if (tid == 0)
            partials[bid] = wred[0][0] + wred[1][0] + wred[2][0] + wred[3][0];
    } else {
        // ---- obj-loss path: one chunk per block, wave per candidate ----
        int cid = bid - 1488;  // 0..1439, same mapping as cand_kernel
        int n = chunkcnt[cid];
        float* op = objpart + (size_t)cid * 4;
        if (n == 0) {
            if (tid == 0) { op[0] = 0.f; op[1] = 0.f; op[2] = 0.f; op[3] = 0.f; }
            return;
        }
        int s, b, spb, Sdim;
        const float *fm, *yt;
        if (cid < 80)       { s = 0; b = cid / 5;  spb = 1083;  Sdim = 19; fm = fm0; yt = yt0; }
        else if (cid < 352) { int l = cid - 80;  s = 1; b = l / 17; spb = 4332;  Sdim = 38; fm = fm1; yt = yt1; }
        else                { int l = cid - 352; s = 2; b = l / 68; spb = 17328; Sdim = 76; fm = fm2; yt = yt2; }
        int HW = Sdim * Sdim;
        float axy = 0.f, awh = 0.f, aconf = 0.f, acls = 0.f;
        for (int ci = wid; ci < n; ci += 4) {
            const float* cd = chunkdata + ((size_t)cid * 256 + ci) * 5;
            float x = cd[0], y = cd[1], w = cd[2], h = cd[3];
            int cell = ((const int*)cd)[4];
            int hw = cell / 3, a = cell - hw * 3;
            int hh = hw / Sdim, ww = hw - hh * Sdim;
            const float* f = fm + ((size_t)(b * 255 + a * 85)) * HW + hw;
            const float* yrow = yt + ((size_t)b * spb + cell) * 85;
            float cl = bcef_(f[(size_t)(5 + lane) * HW], yrow[5 + lane]);
            if (lane < 16) {
                int k2 = 64 + lane;
                cl += bcef_(f[(size_t)(5 + k2) * HW], yrow[5 + k2]);
            }
            acls += cl;
            float bscale = 2.f - w * h;
            if (lane < 5) {
                float lv = f[(size_t)lane * HW];
                if (lane == 0) axy += bscale * bcef_(lv, x * (float)Sdim - (float)ww);
                else if (lane == 1) axy += bscale * bcef_(lv, y * (float)Sdim - (float)hh);
                else if (lane == 2) {
                    float tw = logf(w / d_anch[s][a][0] * 608.f);
                    float d = lv - tw;
                    awh += bscale * d * d;
                } else if (lane == 3) {
                    float th = logf(h / d_anch[s][a][1] * 608.f);
                    float d = lv - th;
                    awh += bscale * d * d;
                } else {
                    aconf += bcef_(lv, 1.0f);
                }
            }
        }
        #pragma unroll
        for (int o = 32; o > 0; o >>= 1) {
            axy += __shfl_down(axy, o);
            awh += __shfl_down(awh, o);
            aconf += __shfl_down(aconf, o);
            acls += __shfl_down(acls, o);
        }
        if (lane == 0) {
            wred[wid][0] = axy; wred[wid][1] = awh;
            wred[wid][2] = aconf; wred[wid][3] = acls;
        }
        __syncthreads();
        if (tid == 0) {
            op[0] = wred[0][0] + wred[1][0] + wred[2][0] + wred[3][0];
            op[1] = wred[0][1] + wred[1][1] + wred[2][1] + wred[3][1];
            op[2] = wred[0][2] + wred[1][2] + wred[2][2] + wred[3][2];
            op[3] = wred[0][3] + wred[1][3] + wred[2][3] + wred[3][3];
        }
    }
}

// ---------------------------------------------------------------------------
// K3: final reduction of 1488 conf partials + 1440x4 obj partials.
// ---------------------------------------------------------------------------
__global__ void finalize_kernel(const float* __restrict__ partials,
                                const float* __restrict__ objpart,
                                float* __restrict__ out) {
    __shared__ float red[4][5];
    int tid = threadIdx.x;  // 256
    int wid = tid >> 6, lane = tid & 63;
    float cno = 0.f;
    for (int i = tid; i < 1488; i += 256) cno += partials[i];
    float xy = 0.f, wh = 0.f, co = 0.f, cl = 0.f;
    for (int i = tid; i < 1440; i += 256) {
        const float* op = objpart + (size_t)i * 4;
        xy += op[0]; wh += op[1]; co += op[2]; cl += op[3];
    }
    #pragma unroll
    for (int o = 32; o > 0; o >>= 1) {
        cno += __shfl_down(cno, o);
        xy += __shfl_down(xy, o);
        wh += __shfl_down(wh, o);
        co += __shfl_down(co, o);
        cl += __shfl_down(cl, o);
    }
    if (lane == 0) {
        red[wid][0] = cno; red[wid][1] = xy; red[wid][2] = wh;
        red[wid][3] = co;  red[wid][4] = cl;
    }
    __syncthreads();
    if (tid == 0) {
        float conf = 0.f, txy = 0.f, twh = 0.f, tcl = 0.f;
        for (int i = 0; i < 4; ++i) {
            conf += red[i][0] + red[i][3];
            txy += red[i][1]; twh += red[i][2]; tcl += red[i][4];
        }
        const float invB = 1.0f / 16.0f;
        float a0 = txy * invB;
        float a1 = twh * invB;
        float a2 = conf * invB;
        float a3 = tcl * invB;
        out[1] = a0; out[2] = a1; out[3] = a2; out[4] = a3;
        out[0] = a0 + a1 + a2 + a3;
    }
}

extern "C" void kernel_launch(void* const* d_in, const int* in_sizes, int n_in,
                              void* d_out, int out_size, void* d_ws, size_t ws_size,
                              hipStream_t stream) {
    const float* fm0 = (const float*)d_in[0];
    const float* fm1 = (const float*)d_in[1];
    const float* fm2 = (const float*)d_in[2];
    const float* yt0 = (const float*)d_in[3];
    const float* yt1 = (const float*)d_in[4];
    const float* yt2 = (const float*)d_in[5];
    float* out = (float*)d_out;

    // workspace layout (bytes); nothing needs pre-zeroing, no atomics anywhere.
    char* ws = (char*)d_ws;
    int* chunkcnt = (int*)ws;                               // 1440*4 = 5760
    float* partials = (float*)(ws + 5760);                  // 1488*4 = 5952
    float* objpart = (float*)(ws + 11712);                  // 1440*16= 23040
    unsigned char* objmask = (unsigned char*)(ws + 34752);  // 363888
    float* chunkdata = (float*)(ws + 398656);               // 1440*256*5*4 = 7372800

    cand_kernel<<<1440, 256, 0, stream>>>(yt0, yt1, yt2, objmask, chunkdata, chunkcnt);
    fused_kernel<<<2928, 256, 0, stream>>>(fm0, fm1, fm2, yt0, yt1, yt2,
                                           objmask, chunkdata, chunkcnt, partials, objpart);
    finalize_kernel<<<1, 256, 0, stream>>>(partials, objpart, out);
}